// Round 1
// baseline (387.550 us; speedup 1.0000x reference)
//
#include <hip/hip_runtime.h>
#include <hip/hip_bf16.h>
#include <stdint.h>

// MHSA fused: B=4, N=2048, D=1024, H=16, Dh=64
// Pipeline: cvt(x) / tcvt(w_qkv) / tcvt(w_out) -> gemm_qkv -> flash attn -> gemm_out

typedef __attribute__((ext_vector_type(8))) __bf16 bf16x8;
typedef __attribute__((ext_vector_type(4))) __bf16 bf16x4;
typedef __attribute__((ext_vector_type(4))) float f32x4;

#define SCALE_ 0.125f

static __device__ __forceinline__ void gload_lds16(const void* g, void* s) {
  // dest = wave-uniform LDS base + lane*16B (HW behavior), 16B per lane
  __builtin_amdgcn_global_load_lds(
      (__attribute__((address_space(1))) unsigned int*)g,
      (__attribute__((address_space(3))) unsigned int*)s, 16, 0, 0);
}

// ---------------- f32 -> bf16 flat convert (vectorized) ----------------
__global__ void k_cvt(const float* __restrict__ src, __bf16* __restrict__ dst, int n4) {
  int i = blockIdx.x * blockDim.x + threadIdx.x;
  if (i >= n4) return;
  float4 v = reinterpret_cast<const float4*>(src)[i];
  bf16x4 o = { (__bf16)v.x, (__bf16)v.y, (__bf16)v.z, (__bf16)v.w };
  *reinterpret_cast<bf16x4*>(dst + (size_t)i * 4) = o;
}

// ---------------- transpose + convert: dst[c][r] = src[r][c], src is Hs x W ----
__global__ void k_tcvt(const float* __restrict__ src, __bf16* __restrict__ dst, int W, int Hs) {
  __shared__ float tile[32][33];
  int tx = threadIdx.x, ty = threadIdx.y;  // 32 x 8
  int x = blockIdx.x * 32 + tx;
  int y0 = blockIdx.y * 32;
  for (int j = ty; j < 32; j += 8) tile[j][tx] = src[(size_t)(y0 + j) * W + x];
  __syncthreads();
  int xo = y0 + tx;
  int yo = blockIdx.x * 32;
  for (int j = ty; j < 32; j += 8) dst[(size_t)(yo + j) * Hs + xo] = (__bf16)tile[tx][j];
}

// ---------------- m97-structure GEMM core: C(128x128) = A[M][K] * BT[N][K]^T ----
// 4 waves, each 64x64 via 4x4 frags of 16x16x32 bf16. BK=32.
static __device__ __forceinline__ void gemm_core(
    const __bf16* __restrict__ A, const __bf16* __restrict__ BT, int K,
    int m0, int n0, f32x4 acc[4][4], __bf16* As, __bf16* Bs) {
  const int tid = threadIdx.x;
  const int lane = tid & 63, w = tid >> 6;
  const int fr = lane & 15, fq = lane >> 4;
  const int srow = lane >> 2, scol = (lane & 3) * 8;  // 64 lanes x 16B = 16 rows of 32 bf16
  const int wr = (w >> 1) * 64, wc = (w & 1) * 64;
#pragma unroll
  for (int mi = 0; mi < 4; ++mi)
#pragma unroll
    for (int nj = 0; nj < 4; ++nj) acc[mi][nj] = (f32x4){0.f, 0.f, 0.f, 0.f};

  for (int ko = 0; ko < K; ko += 32) {
#pragma unroll
    for (int i = 0; i < 2; ++i) {
      int rb = w * 32 + i * 16;
      gload_lds16(A + (size_t)(m0 + rb + srow) * K + ko + scol, As + rb * 32);
      gload_lds16(BT + (size_t)(n0 + rb + srow) * K + ko + scol, Bs + rb * 32);
    }
    __syncthreads();
    bf16x8 af[4], bfv[4];
#pragma unroll
    for (int mi = 0; mi < 4; ++mi)
      af[mi] = *(const bf16x8*)(As + (wr + mi * 16 + fr) * 32 + fq * 8);
#pragma unroll
    for (int nj = 0; nj < 4; ++nj)
      bfv[nj] = *(const bf16x8*)(Bs + (wc + nj * 16 + fr) * 32 + fq * 8);
#pragma unroll
    for (int mi = 0; mi < 4; ++mi)
#pragma unroll
      for (int nj = 0; nj < 4; ++nj)
        acc[mi][nj] = __builtin_amdgcn_mfma_f32_16x16x32_bf16(af[mi], bfv[nj], acc[mi][nj], 0, 0, 0);
    __syncthreads();
  }
}

// C cols 0..3071: [q | k | v]. q,k -> [bh][n][64]; v -> transposed [bh][64][n]
__global__ __launch_bounds__(256) void k_gemm_qkv(
    const __bf16* __restrict__ A, const __bf16* __restrict__ BT,
    __bf16* __restrict__ qb, __bf16* __restrict__ kb, __bf16* __restrict__ vb) {
  __shared__ __align__(16) __bf16 As[128 * 32];
  __shared__ __align__(16) __bf16 Bs[128 * 32];
  f32x4 acc[4][4];
  int m0 = blockIdx.x * 128, n0 = blockIdx.y * 128;
  gemm_core(A, BT, 1024, m0, n0, acc, As, Bs);
  const int lane = threadIdx.x & 63, w = threadIdx.x >> 6;
  const int fr = lane & 15, fq = lane >> 4;
  const int wr = (w >> 1) * 64, wc = (w & 1) * 64;
  const int which = n0 >> 10;  // 128-col tile never crosses a q/k/v boundary
#pragma unroll
  for (int mi = 0; mi < 4; ++mi) {
#pragma unroll
    for (int nj = 0; nj < 4; ++nj) {
      int row = m0 + wr + mi * 16 + fq * 4;          // token index (4 consecutive)
      int col = n0 + wc + nj * 16 + fr;              // qkv column
      int rem = col & 1023, h = rem >> 6, d = rem & 63;
      int bb = row >> 11, n = row & 2047;            // row..row+3 stay in one b
      int bh = bb * 16 + h;
      if (which == 2) {
        bf16x4 pk = { (__bf16)acc[mi][nj][0], (__bf16)acc[mi][nj][1],
                      (__bf16)acc[mi][nj][2], (__bf16)acc[mi][nj][3] };
        *reinterpret_cast<bf16x4*>(vb + ((size_t)bh * 64 + d) * 2048 + n) = pk;
      } else {
        __bf16* dst = (which == 0) ? qb : kb;
#pragma unroll
        for (int j = 0; j < 4; ++j)
          dst[((size_t)bh * 2048 + (n + j)) * 64 + d] = (__bf16)acc[mi][nj][j];
      }
    }
  }
}

__global__ __launch_bounds__(256) void k_gemm_out(
    const __bf16* __restrict__ A, const __bf16* __restrict__ BT, float* __restrict__ C) {
  __shared__ __align__(16) __bf16 As[128 * 32];
  __shared__ __align__(16) __bf16 Bs[128 * 32];
  f32x4 acc[4][4];
  int m0 = blockIdx.x * 128, n0 = blockIdx.y * 128;
  gemm_core(A, BT, 1024, m0, n0, acc, As, Bs);
  const int lane = threadIdx.x & 63, w = threadIdx.x >> 6;
  const int fr = lane & 15, fq = lane >> 4;
  const int wr = (w >> 1) * 64, wc = (w & 1) * 64;
#pragma unroll
  for (int mi = 0; mi < 4; ++mi)
#pragma unroll
    for (int nj = 0; nj < 4; ++nj)
#pragma unroll
      for (int j = 0; j < 4; ++j)
        C[(size_t)(m0 + wr + mi * 16 + fq * 4 + j) * 1024 + n0 + wc + nj * 16 + fr] =
            acc[mi][nj][j];
}

// ---------------- flash attention: block = (b,h) x 64 q-rows, 4 waves x 16 rows ----
__global__ __launch_bounds__(256) void k_attn(
    const __bf16* __restrict__ qb, const __bf16* __restrict__ kb,
    const __bf16* __restrict__ vb, __bf16* __restrict__ ao) {
  __shared__ __align__(16) __bf16 Ks[64 * 64];      // [key][d]
  __shared__ __align__(16) __bf16 Vs[64 * 64];      // [d][key]  (vb is pre-transposed)
  __shared__ __align__(16) __bf16 Ps[4][16 * 64];   // per-wave [qrow][key]
  const int tid = threadIdx.x, lane = tid & 63, w = tid >> 6;
  const int fr = lane & 15, fq = lane >> 4;
  const int bh = blockIdx.y, qt = blockIdx.x;
  const int qrow = qt * 64 + w * 16 + fr;
  const __bf16* qptr = qb + ((size_t)bh * 2048 + qrow) * 64;
  bf16x8 qf0 = *(const bf16x8*)(qptr + fq * 8);
  bf16x8 qf1 = *(const bf16x8*)(qptr + 32 + fq * 8);
  f32x4 acc[4];
  float m[4], lsum[4];
#pragma unroll
  for (int j = 0; j < 4; ++j) { acc[j] = (f32x4){0, 0, 0, 0}; m[j] = -1e30f; lsum[j] = 0.f; }
  const int sr = lane >> 3, sc = (lane & 7) * 8;  // 64 lanes x 16B = 8 rows of 64 bf16

  for (int kt = 0; kt < 32; ++kt) {
    const int j0 = kt * 64;
#pragma unroll
    for (int i = 0; i < 2; ++i) {
      int rb = w * 16 + i * 8;
      gload_lds16(kb + ((size_t)bh * 2048 + j0 + rb + sr) * 64 + sc, Ks + rb * 64);
      gload_lds16(vb + ((size_t)bh * 64 + rb + sr) * 2048 + j0 + sc, Vs + rb * 64);
    }
    __syncthreads();
    // S = Q K^T  (16 x 64 per wave)
    f32x4 sf[4];
#pragma unroll
    for (int nj = 0; nj < 4; ++nj) {
      bf16x8 k0 = *(const bf16x8*)(Ks + (nj * 16 + fr) * 64 + fq * 8);
      bf16x8 k1 = *(const bf16x8*)(Ks + (nj * 16 + fr) * 64 + 32 + fq * 8);
      f32x4 z = (f32x4){0, 0, 0, 0};
      z = __builtin_amdgcn_mfma_f32_16x16x32_bf16(qf0, k0, z, 0, 0, 0);
      z = __builtin_amdgcn_mfma_f32_16x16x32_bf16(qf1, k1, z, 0, 0, 0);
      sf[nj] = z;
    }
    // online softmax (rows fq*4+j; cols across 16 lanes x 4 frags)
    float corr[4];
#pragma unroll
    for (int j = 0; j < 4; ++j) {
      float s0 = sf[0][j] * SCALE_, s1 = sf[1][j] * SCALE_;
      float s2 = sf[2][j] * SCALE_, s3 = sf[3][j] * SCALE_;
      sf[0][j] = s0; sf[1][j] = s1; sf[2][j] = s2; sf[3][j] = s3;
      float mt = fmaxf(fmaxf(s0, s1), fmaxf(s2, s3));
#pragma unroll
      for (int off = 1; off < 16; off <<= 1) mt = fmaxf(mt, __shfl_xor(mt, off, 64));
      float mn = fmaxf(m[j], mt);
      corr[j] = __expf(m[j] - mn);
      m[j] = mn;
      float rs = 0.f;
#pragma unroll
      for (int nj = 0; nj < 4; ++nj) {
        float p = __expf(sf[nj][j] - mn);
        sf[nj][j] = p;
        rs += p;
      }
#pragma unroll
      for (int off = 1; off < 16; off <<= 1) rs += __shfl_xor(rs, off, 64);
      lsum[j] = lsum[j] * corr[j] + rs;
    }
#pragma unroll
    for (int dj = 0; dj < 4; ++dj) {
      acc[dj][0] *= corr[0]; acc[dj][1] *= corr[1];
      acc[dj][2] *= corr[2]; acc[dj][3] *= corr[3];
    }
    // P (C-layout) -> LDS -> A-fragment layout
#pragma unroll
    for (int nj = 0; nj < 4; ++nj)
#pragma unroll
      for (int j = 0; j < 4; ++j)
        Ps[w][(fq * 4 + j) * 64 + nj * 16 + fr] = (__bf16)sf[nj][j];
    __syncthreads();
    // O += P V
#pragma unroll
    for (int ks = 0; ks < 2; ++ks) {
      bf16x8 pa = *(const bf16x8*)(Ps[w] + fr * 64 + ks * 32 + fq * 8);
#pragma unroll
      for (int dj = 0; dj < 4; ++dj) {
        bf16x8 vf = *(const bf16x8*)(Vs + (dj * 16 + fr) * 64 + ks * 32 + fq * 8);
        acc[dj] = __builtin_amdgcn_mfma_f32_16x16x32_bf16(pa, vf, acc[dj], 0, 0, 0);
      }
    }
    __syncthreads();
  }
  const int b = bh >> 4, h = bh & 15;
#pragma unroll
  for (int dj = 0; dj < 4; ++dj)
#pragma unroll
    for (int j = 0; j < 4; ++j) {
      int n = qt * 64 + w * 16 + fq * 4 + j;
      int d = dj * 16 + fr;
      ao[((size_t)(b * 2048 + n)) * 1024 + h * 64 + d] = (__bf16)(acc[dj][j] / lsum[j]);
    }
}

extern "C" void kernel_launch(void* const* d_in, const int* in_sizes, int n_in,
                              void* d_out, int out_size, void* d_ws, size_t ws_size,
                              hipStream_t stream) {
  (void)in_sizes; (void)n_in; (void)out_size; (void)ws_size;
  const float* x = (const float*)d_in[0];      // [4,2048,1024]
  const float* w_qkv = (const float*)d_in[1];  // [1024,3072]
  const float* w_out = (const float*)d_in[2];  // [1024,1024]
  float* out = (float*)d_out;                  // [4,2048,1024]

  char* p = (char*)d_ws;
  __bf16* xb    = (__bf16*)p; p += (size_t)8192 * 1024 * 2;  // x bf16 [8192][1024]
  __bf16* wqkvT = (__bf16*)p; p += (size_t)3072 * 1024 * 2;  // w_qkv^T [3072][1024]
  __bf16* woutT = (__bf16*)p; p += (size_t)1024 * 1024 * 2;  // w_out^T [1024][1024]
  __bf16* qb    = (__bf16*)p; p += (size_t)64 * 2048 * 64 * 2;  // [bh][n][d]
  __bf16* kb    = (__bf16*)p; p += (size_t)64 * 2048 * 64 * 2;  // [bh][n][d]
  __bf16* vb    = (__bf16*)p; p += (size_t)64 * 64 * 2048 * 2;  // [bh][d][n]
  __bf16* ao    = (__bf16*)p; p += (size_t)8192 * 1024 * 2;     // [b*n][h*d]

  k_cvt<<<8192, 256, 0, stream>>>(x, xb, 2097152);
  k_tcvt<<<dim3(96, 32), dim3(32, 8), 0, stream>>>(w_qkv, wqkvT, 3072, 1024);
  k_tcvt<<<dim3(32, 32), dim3(32, 8), 0, stream>>>(w_out, woutT, 1024, 1024);
  k_gemm_qkv<<<dim3(64, 24), 256, 0, stream>>>(xb, wqkvT, qb, kb, vb);
  k_attn<<<dim3(32, 64), 256, 0, stream>>>(qb, kb, vb, ao);
  k_gemm_out<<<dim3(64, 8), 256, 0, stream>>>(ao, woutT, out);
}

// Round 2
// 321.802 us; speedup vs baseline: 1.2043x; 1.2043x over previous
//
#include <hip/hip_runtime.h>
#include <hip/hip_bf16.h>
#include <stdint.h>

// MHSA fused: B=4, N=2048, D=1024, H=16, Dh=64
// Pipeline: cvt(x) / tcvt(w_qkv) / tcvt(w_out) -> gemm_qkv -> flash attn -> gemm_out

typedef __attribute__((ext_vector_type(8))) __bf16 bf16x8;
typedef __attribute__((ext_vector_type(4))) __bf16 bf16x4;
typedef __attribute__((ext_vector_type(4))) float f32x4;

// 0.125 (head-dim scale) * log2(e): applied inside exp2 args in f32 — exact math path
#define EXPC 0.18033688011112042f

static __device__ __forceinline__ void gload_lds16(const void* g, void* s) {
  // dest = wave-uniform LDS base + lane*16B (HW behavior), 16B per lane
  __builtin_amdgcn_global_load_lds(
      (__attribute__((address_space(1))) unsigned int*)g,
      (__attribute__((address_space(3))) unsigned int*)s, 16, 0, 0);
}

// ---------------- f32 -> bf16 flat convert (vectorized) ----------------
__global__ void k_cvt(const float* __restrict__ src, __bf16* __restrict__ dst, int n4) {
  int i = blockIdx.x * blockDim.x + threadIdx.x;
  if (i >= n4) return;
  float4 v = reinterpret_cast<const float4*>(src)[i];
  bf16x4 o = { (__bf16)v.x, (__bf16)v.y, (__bf16)v.z, (__bf16)v.w };
  *reinterpret_cast<bf16x4*>(dst + (size_t)i * 4) = o;
}

// ---------------- transpose + convert: dst[c][r] = src[r][c], src is Hs x W ----
__global__ void k_tcvt(const float* __restrict__ src, __bf16* __restrict__ dst, int W, int Hs) {
  __shared__ float tile[32][33];
  int tx = threadIdx.x, ty = threadIdx.y;  // 32 x 8
  int x = blockIdx.x * 32 + tx;
  int y0 = blockIdx.y * 32;
  for (int j = ty; j < 32; j += 8) tile[j][tx] = src[(size_t)(y0 + j) * W + x];
  __syncthreads();
  int xo = y0 + tx;
  int yo = blockIdx.x * 32;
  for (int j = ty; j < 32; j += 8) dst[(size_t)(yo + j) * Hs + xo] = (__bf16)tile[tx][j];
}

// ---------------- m97-structure GEMM core: C(128x128) = A[M][K] * BT[N][K]^T ----
// 4 waves, each 64x64 via 4x4 frags of 16x16x32 bf16. BK=32.
static __device__ __forceinline__ void gemm_core(
    const __bf16* __restrict__ A, const __bf16* __restrict__ BT, int K,
    int m0, int n0, f32x4 acc[4][4], __bf16* As, __bf16* Bs) {
  const int tid = threadIdx.x;
  const int lane = tid & 63, w = tid >> 6;
  const int fr = lane & 15, fq = lane >> 4;
  const int srow = lane >> 2, scol = (lane & 3) * 8;  // 64 lanes x 16B = 16 rows of 32 bf16
  const int wr = (w >> 1) * 64, wc = (w & 1) * 64;
#pragma unroll
  for (int mi = 0; mi < 4; ++mi)
#pragma unroll
    for (int nj = 0; nj < 4; ++nj) acc[mi][nj] = (f32x4){0.f, 0.f, 0.f, 0.f};

  for (int ko = 0; ko < K; ko += 32) {
#pragma unroll
    for (int i = 0; i < 2; ++i) {
      int rb = w * 32 + i * 16;
      gload_lds16(A + (size_t)(m0 + rb + srow) * K + ko + scol, As + rb * 32);
      gload_lds16(BT + (size_t)(n0 + rb + srow) * K + ko + scol, Bs + rb * 32);
    }
    __syncthreads();
    bf16x8 af[4], bfv[4];
#pragma unroll
    for (int mi = 0; mi < 4; ++mi)
      af[mi] = *(const bf16x8*)(As + (wr + mi * 16 + fr) * 32 + fq * 8);
#pragma unroll
    for (int nj = 0; nj < 4; ++nj)
      bfv[nj] = *(const bf16x8*)(Bs + (wc + nj * 16 + fr) * 32 + fq * 8);
#pragma unroll
    for (int mi = 0; mi < 4; ++mi)
#pragma unroll
      for (int nj = 0; nj < 4; ++nj)
        acc[mi][nj] = __builtin_amdgcn_mfma_f32_16x16x32_bf16(af[mi], bfv[nj], acc[mi][nj], 0, 0, 0);
    __syncthreads();
  }
}

// C cols 0..3071: [q | k | v]. q,k -> [bh][n][64]; v -> transposed [bh][64][n]
__global__ __launch_bounds__(256) void k_gemm_qkv(
    const __bf16* __restrict__ A, const __bf16* __restrict__ BT,
    __bf16* __restrict__ qb, __bf16* __restrict__ kb, __bf16* __restrict__ vb) {
  __shared__ __align__(16) __bf16 As[128 * 32];
  __shared__ __align__(16) __bf16 Bs[128 * 32];
  f32x4 acc[4][4];
  int m0 = blockIdx.x * 128, n0 = blockIdx.y * 128;
  gemm_core(A, BT, 1024, m0, n0, acc, As, Bs);
  const int lane = threadIdx.x & 63, w = threadIdx.x >> 6;
  const int fr = lane & 15, fq = lane >> 4;
  const int wr = (w >> 1) * 64, wc = (w & 1) * 64;
  const int which = n0 >> 10;  // 128-col tile never crosses a q/k/v boundary
#pragma unroll
  for (int mi = 0; mi < 4; ++mi) {
#pragma unroll
    for (int nj = 0; nj < 4; ++nj) {
      int row = m0 + wr + mi * 16 + fq * 4;          // token index (4 consecutive)
      int col = n0 + wc + nj * 16 + fr;              // qkv column
      int rem = col & 1023, h = rem >> 6, d = rem & 63;
      int bb = row >> 11, n = row & 2047;            // row..row+3 stay in one b
      int bh = bb * 16 + h;
      if (which == 2) {
        bf16x4 pk = { (__bf16)acc[mi][nj][0], (__bf16)acc[mi][nj][1],
                      (__bf16)acc[mi][nj][2], (__bf16)acc[mi][nj][3] };
        *reinterpret_cast<bf16x4*>(vb + ((size_t)bh * 64 + d) * 2048 + n) = pk;
      } else {
        __bf16* dst = (which == 0) ? qb : kb;
#pragma unroll
        for (int j = 0; j < 4; ++j)
          dst[((size_t)bh * 2048 + (n + j)) * 64 + d] = (__bf16)acc[mi][nj][j];
      }
    }
  }
}

__global__ __launch_bounds__(256) void k_gemm_out(
    const __bf16* __restrict__ A, const __bf16* __restrict__ BT, float* __restrict__ C) {
  __shared__ __align__(16) __bf16 As[128 * 32];
  __shared__ __align__(16) __bf16 Bs[128 * 32];
  f32x4 acc[4][4];
  int m0 = blockIdx.x * 128, n0 = blockIdx.y * 128;
  gemm_core(A, BT, 1024, m0, n0, acc, As, Bs);
  const int lane = threadIdx.x & 63, w = threadIdx.x >> 6;
  const int fr = lane & 15, fq = lane >> 4;
  const int wr = (w >> 1) * 64, wc = (w & 1) * 64;
#pragma unroll
  for (int mi = 0; mi < 4; ++mi)
#pragma unroll
    for (int nj = 0; nj < 4; ++nj)
#pragma unroll
      for (int j = 0; j < 4; ++j)
        C[(size_t)(m0 + wr + mi * 16 + fq * 4 + j) * 1024 + n0 + wc + nj * 16 + fr] =
            acc[mi][nj][j];
}

// ---------------- flash attention: block = (b,h) x 64 q-rows, 4 waves x 16 rows ----
// LDS tiles XOR-swizzled: stored[row][chunk] = logical[row][chunk ^ (row&7)]
// (chunk = 16B unit; achieved via pre-swizzled global_load_lds source + swizzled reads)
__global__ __launch_bounds__(256) void k_attn(
    const __bf16* __restrict__ qb, const __bf16* __restrict__ kb,
    const __bf16* __restrict__ vb, __bf16* __restrict__ ao) {
  __shared__ __align__(16) __bf16 Ks[2][64 * 64];   // [key][d], swizzled, double-buffered
  __shared__ __align__(16) __bf16 Vs[2][64 * 64];   // [d][key], swizzled (vb pre-transposed)
  __shared__ __align__(16) __bf16 Ps[4][16 * 64];   // per-wave [qrow][key], swizzled
  const int tid = threadIdx.x, lane = tid & 63, w = tid >> 6;
  const int fr = lane & 15, fq = lane >> 4;
  const int fr7 = fr & 7;
  const int bh = blockIdx.y, qt = blockIdx.x;
  const int sr = lane >> 3;                 // staging: row within 8-row group
  const int gc = (lane & 7) ^ sr;           // staging: pre-swizzled source chunk
  const __bf16* kbase = kb + (size_t)bh * 2048 * 64;
  const __bf16* vbase = vb + (size_t)bh * 64 * 2048;

  const int qrow = qt * 64 + w * 16 + fr;
  const __bf16* qptr = qb + ((size_t)bh * 2048 + qrow) * 64;
  bf16x8 qf0 = *(const bf16x8*)(qptr + fq * 8);
  bf16x8 qf1 = *(const bf16x8*)(qptr + 32 + fq * 8);

  f32x4 acc[4];
  float m[4], lsum[4];
#pragma unroll
  for (int j = 0; j < 4; ++j) { acc[j] = (f32x4){0, 0, 0, 0}; m[j] = -1e30f; lsum[j] = 0.f; }

  // stage one 64-key tile (K + V^T) into buffer `buf`
  auto stage = [&](int buf, int j0) {
#pragma unroll
    for (int i = 0; i < 2; ++i) {
      int rb = w * 16 + i * 8;
      gload_lds16(kbase + (size_t)(j0 + rb + sr) * 64 + gc * 8, &Ks[buf][rb * 64]);
      gload_lds16(vbase + (size_t)(rb + sr) * 2048 + j0 + gc * 8, &Vs[buf][rb * 64]);
    }
  };

  stage(0, 0);
  __syncthreads();

  for (int kt = 0; kt < 32; ++kt) {
    const int cur = kt & 1;
    if (kt < 31) stage(cur ^ 1, (kt + 1) * 64);   // prefetch next tile (overlaps compute)

    // ---- S = Q K^T (16 x 64 per wave), swizzled K reads ----
    f32x4 sf[4];
    const int c0 = fq ^ fr7;
    __builtin_amdgcn_s_setprio(1);
#pragma unroll
    for (int nj = 0; nj < 4; ++nj) {
      const __bf16* kr = &Ks[cur][(nj * 16 + fr) * 64];
      bf16x8 k0 = *(const bf16x8*)(kr + (c0 << 3));
      bf16x8 k1 = *(const bf16x8*)(kr + ((c0 ^ 4) << 3));
      f32x4 z = (f32x4){0, 0, 0, 0};
      z = __builtin_amdgcn_mfma_f32_16x16x32_bf16(qf0, k0, z, 0, 0, 0);
      z = __builtin_amdgcn_mfma_f32_16x16x32_bf16(qf1, k1, z, 0, 0, 0);
      sf[nj] = z;
    }
    __builtin_amdgcn_s_setprio(0);

    // ---- online softmax in exp2 domain (raw-score max tracking) ----
    float corr[4];
#pragma unroll
    for (int j = 0; j < 4; ++j) {
      float mt = fmaxf(fmaxf(sf[0][j], sf[1][j]), fmaxf(sf[2][j], sf[3][j]));
#pragma unroll
      for (int off = 1; off < 16; off <<= 1) mt = fmaxf(mt, __shfl_xor(mt, off, 64));
      float mn = fmaxf(m[j], mt);
      corr[j] = __builtin_amdgcn_exp2f((m[j] - mn) * EXPC);
      m[j] = mn;
      float rs = 0.f;
#pragma unroll
      for (int nj = 0; nj < 4; ++nj) {
        float p = __builtin_amdgcn_exp2f((sf[nj][j] - mn) * EXPC);
        sf[nj][j] = p;
        rs += p;
      }
#pragma unroll
      for (int off = 1; off < 16; off <<= 1) rs += __shfl_xor(rs, off, 64);
      lsum[j] = lsum[j] * corr[j] + rs;
    }
#pragma unroll
    for (int dj = 0; dj < 4; ++dj) {
      acc[dj][0] *= corr[0]; acc[dj][1] *= corr[1];
      acc[dj][2] *= corr[2]; acc[dj][3] *= corr[3];
    }

    // ---- P (C-layout) -> per-wave LDS (swizzled) -> A-fragment layout ----
#pragma unroll
    for (int nj = 0; nj < 4; ++nj)
#pragma unroll
      for (int j = 0; j < 4; ++j) {
        int prow = fq * 4 + j;
        int pchunk = (nj * 2 + (fr >> 3)) ^ (prow & 7);
        Ps[w][prow * 64 + (pchunk << 3) + fr7] = (__bf16)sf[nj][j];
      }

    // ---- O += P V, swizzled P/V reads ----
    __builtin_amdgcn_s_setprio(1);
#pragma unroll
    for (int ks = 0; ks < 2; ++ks) {
      bf16x8 pa = *(const bf16x8*)(&Ps[w][fr * 64 + (((ks * 4 + fq) ^ fr7) << 3)]);
#pragma unroll
      for (int dj = 0; dj < 4; ++dj) {
        bf16x8 vf = *(const bf16x8*)(&Vs[cur][(dj * 16 + fr) * 64 + (((ks * 4 + fq) ^ fr7) << 3)]);
        acc[dj] = __builtin_amdgcn_mfma_f32_16x16x32_bf16(pa, vf, acc[dj], 0, 0, 0);
      }
    }
    __builtin_amdgcn_s_setprio(0);

    __syncthreads();  // drains this wave's prefetch (hidden under compute) + barrier
  }

  const int b = bh >> 4, h = bh & 15;
  float inv[4];
#pragma unroll
  for (int j = 0; j < 4; ++j) inv[j] = 1.0f / lsum[j];
#pragma unroll
  for (int dj = 0; dj < 4; ++dj)
#pragma unroll
    for (int j = 0; j < 4; ++j) {
      int n = qt * 64 + w * 16 + fq * 4 + j;
      int d = dj * 16 + fr;
      ao[((size_t)(b * 2048 + n)) * 1024 + h * 64 + d] = (__bf16)(acc[dj][j] * inv[j]);
    }
}

extern "C" void kernel_launch(void* const* d_in, const int* in_sizes, int n_in,
                              void* d_out, int out_size, void* d_ws, size_t ws_size,
                              hipStream_t stream) {
  (void)in_sizes; (void)n_in; (void)out_size; (void)ws_size;
  const float* x = (const float*)d_in[0];      // [4,2048,1024]
  const float* w_qkv = (const float*)d_in[1];  // [1024,3072]
  const float* w_out = (const float*)d_in[2];  // [1024,1024]
  float* out = (float*)d_out;                  // [4,2048,1024]

  char* p = (char*)d_ws;
  __bf16* xb    = (__bf16*)p; p += (size_t)8192 * 1024 * 2;  // x bf16 [8192][1024]
  __bf16* wqkvT = (__bf16*)p; p += (size_t)3072 * 1024 * 2;  // w_qkv^T [3072][1024]
  __bf16* woutT = (__bf16*)p; p += (size_t)1024 * 1024 * 2;  // w_out^T [1024][1024]
  __bf16* qb    = (__bf16*)p; p += (size_t)64 * 2048 * 64 * 2;  // [bh][n][d]
  __bf16* kb    = (__bf16*)p; p += (size_t)64 * 2048 * 64 * 2;  // [bh][n][d]
  __bf16* vb    = (__bf16*)p; p += (size_t)64 * 64 * 2048 * 2;  // [bh][d][n]
  __bf16* ao    = (__bf16*)p; p += (size_t)8192 * 1024 * 2;     // [b*n][h*d]

  k_cvt<<<8192, 256, 0, stream>>>(x, xb, 2097152);
  k_tcvt<<<dim3(96, 32), dim3(32, 8), 0, stream>>>(w_qkv, wqkvT, 3072, 1024);
  k_tcvt<<<dim3(32, 32), dim3(32, 8), 0, stream>>>(w_out, woutT, 1024, 1024);
  k_gemm_qkv<<<dim3(64, 24), 256, 0, stream>>>(xb, wqkvT, qb, kb, vb);
  k_attn<<<dim3(32, 64), 256, 0, stream>>>(qb, kb, vb, ao);
  k_gemm_out<<<dim3(64, 8), 256, 0, stream>>>(ao, woutT, out);
}

// Round 3
// 222.037 us; speedup vs baseline: 1.7454x; 1.4493x over previous
//
#include <hip/hip_runtime.h>
#include <hip/hip_bf16.h>
#include <stdint.h>

// MHSA fused: B=4, N=2048, D=1024, H=16, Dh=64
// Pipeline: cvt(x) / tcvt(w_qkv) / tcvt(w_out) -> gemm_qkv -> flash attn -> gemm_out

typedef __attribute__((ext_vector_type(8))) __bf16 bf16x8;
typedef __attribute__((ext_vector_type(4))) __bf16 bf16x4;
typedef __attribute__((ext_vector_type(4))) float f32x4;
typedef __attribute__((ext_vector_type(16))) float f32x16;
typedef __attribute__((ext_vector_type(4))) unsigned int u32x4;

// 0.125 (head-dim scale) * log2(e)
#define EXPC 0.18033688011112042f
// defer-max threshold in raw-score units (0.125*64 = 8 nats -> p <= e^8 fits bf16 easily)
#define THRR 64.0f

static __device__ __forceinline__ void gload_lds16(const void* g, void* s) {
  // dest = wave-uniform LDS base + lane*16B (HW behavior), 16B per lane
  __builtin_amdgcn_global_load_lds(
      (__attribute__((address_space(1))) unsigned int*)g,
      (__attribute__((address_space(3))) unsigned int*)s, 16, 0, 0);
}

static __device__ __forceinline__ unsigned pk2(float lo, float hi) {
  unsigned short a = __builtin_bit_cast(unsigned short, (__bf16)lo);
  unsigned short b = __builtin_bit_cast(unsigned short, (__bf16)hi);
  return (unsigned)a | ((unsigned)b << 16);
}

// ---------------- f32 -> bf16 flat convert (vectorized) ----------------
__global__ void k_cvt(const float* __restrict__ src, __bf16* __restrict__ dst, int n4) {
  int i = blockIdx.x * blockDim.x + threadIdx.x;
  if (i >= n4) return;
  float4 v = reinterpret_cast<const float4*>(src)[i];
  bf16x4 o = { (__bf16)v.x, (__bf16)v.y, (__bf16)v.z, (__bf16)v.w };
  *reinterpret_cast<bf16x4*>(dst + (size_t)i * 4) = o;
}

// ---------------- transpose + convert: dst[c][r] = src[r][c], src is Hs x W ----
__global__ void k_tcvt(const float* __restrict__ src, __bf16* __restrict__ dst, int W, int Hs) {
  __shared__ float tile[32][33];
  int tx = threadIdx.x, ty = threadIdx.y;  // 32 x 8
  int x = blockIdx.x * 32 + tx;
  int y0 = blockIdx.y * 32;
  for (int j = ty; j < 32; j += 8) tile[j][tx] = src[(size_t)(y0 + j) * W + x];
  __syncthreads();
  int xo = y0 + tx;
  int yo = blockIdx.x * 32;
  for (int j = ty; j < 32; j += 8) dst[(size_t)(yo + j) * Hs + xo] = (__bf16)tile[tx][j];
}

// ---------------- m97-structure GEMM core: C(128x128) = A[M][K] * BT[N][K]^T ----
// 4 waves, each 64x64 via 4x4 frags of 16x16x32 bf16. BK=32.
static __device__ __forceinline__ void gemm_core(
    const __bf16* __restrict__ A, const __bf16* __restrict__ BT, int K,
    int m0, int n0, f32x4 acc[4][4], __bf16* As, __bf16* Bs) {
  const int tid = threadIdx.x;
  const int lane = tid & 63, w = tid >> 6;
  const int fr = lane & 15, fq = lane >> 4;
  const int srow = lane >> 2, scol = (lane & 3) * 8;  // 64 lanes x 16B = 16 rows of 32 bf16
  const int wr = (w >> 1) * 64, wc = (w & 1) * 64;
#pragma unroll
  for (int mi = 0; mi < 4; ++mi)
#pragma unroll
    for (int nj = 0; nj < 4; ++nj) acc[mi][nj] = (f32x4){0.f, 0.f, 0.f, 0.f};

  for (int ko = 0; ko < K; ko += 32) {
#pragma unroll
    for (int i = 0; i < 2; ++i) {
      int rb = w * 32 + i * 16;
      gload_lds16(A + (size_t)(m0 + rb + srow) * K + ko + scol, As + rb * 32);
      gload_lds16(BT + (size_t)(n0 + rb + srow) * K + ko + scol, Bs + rb * 32);
    }
    __syncthreads();
    bf16x8 af[4], bfv[4];
#pragma unroll
    for (int mi = 0; mi < 4; ++mi)
      af[mi] = *(const bf16x8*)(As + (wr + mi * 16 + fr) * 32 + fq * 8);
#pragma unroll
    for (int nj = 0; nj < 4; ++nj)
      bfv[nj] = *(const bf16x8*)(Bs + (wc + nj * 16 + fr) * 32 + fq * 8);
#pragma unroll
    for (int mi = 0; mi < 4; ++mi)
#pragma unroll
      for (int nj = 0; nj < 4; ++nj)
        acc[mi][nj] = __builtin_amdgcn_mfma_f32_16x16x32_bf16(af[mi], bfv[nj], acc[mi][nj], 0, 0, 0);
    __syncthreads();
  }
}

// C cols 0..3071: [q | k | v]. q,k -> [bh][n][64]; v -> transposed [bh][64][n]
__global__ __launch_bounds__(256) void k_gemm_qkv(
    const __bf16* __restrict__ A, const __bf16* __restrict__ BT,
    __bf16* __restrict__ qb, __bf16* __restrict__ kb, __bf16* __restrict__ vb) {
  __shared__ __align__(16) __bf16 As[128 * 32];
  __shared__ __align__(16) __bf16 Bs[128 * 32];
  f32x4 acc[4][4];
  int m0 = blockIdx.x * 128, n0 = blockIdx.y * 128;
  gemm_core(A, BT, 1024, m0, n0, acc, As, Bs);
  const int lane = threadIdx.x & 63, w = threadIdx.x >> 6;
  const int fr = lane & 15, fq = lane >> 4;
  const int wr = (w >> 1) * 64, wc = (w & 1) * 64;
  const int which = n0 >> 10;  // 128-col tile never crosses a q/k/v boundary
#pragma unroll
  for (int mi = 0; mi < 4; ++mi) {
#pragma unroll
    for (int nj = 0; nj < 4; ++nj) {
      int row = m0 + wr + mi * 16 + fq * 4;          // token index (4 consecutive)
      int col = n0 + wc + nj * 16 + fr;              // qkv column
      int rem = col & 1023, h = rem >> 6, d = rem & 63;
      int bb = row >> 11, n = row & 2047;            // row..row+3 stay in one b
      int bh = bb * 16 + h;
      if (which == 2) {
        bf16x4 pk = { (__bf16)acc[mi][nj][0], (__bf16)acc[mi][nj][1],
                      (__bf16)acc[mi][nj][2], (__bf16)acc[mi][nj][3] };
        *reinterpret_cast<bf16x4*>(vb + ((size_t)bh * 64 + d) * 2048 + n) = pk;
      } else {
        __bf16* dst = (which == 0) ? qb : kb;
#pragma unroll
        for (int j = 0; j < 4; ++j)
          dst[((size_t)bh * 2048 + (n + j)) * 64 + d] = (__bf16)acc[mi][nj][j];
      }
    }
  }
}

__global__ __launch_bounds__(256) void k_gemm_out(
    const __bf16* __restrict__ A, const __bf16* __restrict__ BT, float* __restrict__ C) {
  __shared__ __align__(16) __bf16 As[128 * 32];
  __shared__ __align__(16) __bf16 Bs[128 * 32];
  f32x4 acc[4][4];
  int m0 = blockIdx.x * 128, n0 = blockIdx.y * 128;
  gemm_core(A, BT, 1024, m0, n0, acc, As, Bs);
  const int lane = threadIdx.x & 63, w = threadIdx.x >> 6;
  const int fr = lane & 15, fq = lane >> 4;
  const int wr = (w >> 1) * 64, wc = (w & 1) * 64;
#pragma unroll
  for (int mi = 0; mi < 4; ++mi)
#pragma unroll
    for (int nj = 0; nj < 4; ++nj)
#pragma unroll
      for (int j = 0; j < 4; ++j)
        C[(size_t)(m0 + wr + mi * 16 + fq * 4 + j) * 1024 + n0 + wc + nj * 16 + fr] =
            acc[mi][nj][j];
}

// ---------------- flash attention, m214-style 8-warp 32x32 swapped structure ----
// Block = (b,h) x 256 q-rows; 8 warps x 32 q-rows. KVBLK=64, D=64.
// Swapped QK^T: S^T = mfma(K, Q) -> lane (q=l&31) holds P for 32 keys (16 per half-lane,
// keys = kb*32 + crow(r,hi), crow = (r&3)+8*(r>>2)+4*hi). Softmax fully in-register.
// P -> PV A-frags via bf16 pack + v_permlane32_swap (no LDS roundtrip).
// K/V LDS: [row][64] bf16 rows (128B), 16B-chunk XOR swizzle c ^= (row&7) ^ ((row>>3)&3)
// -> conflict-free b128 reads; staged via pre-swizzled-source global_load_lds.
__global__ __launch_bounds__(512, 1) void k_attn(
    const __bf16* __restrict__ qb, const __bf16* __restrict__ kb,
    const __bf16* __restrict__ vb, __bf16* __restrict__ ao) {
  __shared__ __align__(16) __bf16 Ks[2][64 * 64];   // [key][d], swizzled
  __shared__ __align__(16) __bf16 Vs[2][64 * 64];   // [d][key], swizzled (vb pre-transposed)
  const int tid = threadIdx.x, lane = tid & 63, w = tid >> 6;
  const int r31 = lane & 31, hi = lane >> 5;
  const int lsw = (lane & 7) ^ ((lane >> 3) & 3);   // read-side chunk swizzle
  const int bh = blockIdx.x & 63, qblk = blockIdx.x >> 6;  // same-bh blocks land on one XCD
  const __bf16* kbase = kb + (size_t)bh * 2048 * 64;
  const __bf16* vbase = vb + (size_t)bh * 64 * 2048;

  // staging coords: thread -> (row = tid>>3, chunk-pos = tid&7), source chunk pre-swizzled
  const int srow = tid >> 3;
  const int ssc = (tid & 7) ^ (srow & 7) ^ ((srow >> 3) & 3);
  const int wid = tid >> 6;

  // Q resident in registers: B-operand frag = Q[q=l&31][d = dd*16 + hi*8 + j]
  const int nbase = qblk * 256 + w * 32;
  const __bf16* qptr = qb + ((size_t)bh * 2048 + nbase + r31) * 64;
  bf16x8 qf[4];
#pragma unroll
  for (int dd = 0; dd < 4; ++dd)
    qf[dd] = *(const bf16x8*)(qptr + dd * 16 + hi * 8);

  f32x16 o0, o1;   // O accum: rows q=crow(r,hi), cols d = dblk*32 + (l&31)
#pragma unroll
  for (int r = 0; r < 16; ++r) { o0[r] = 0.f; o1[r] = 0.f; }
  float m = -1e30f, lsum = 0.f;  // per q-row (q = l&31); lsum = own-half partial

  auto stage = [&](int buf, int j0) {
    gload_lds16(kbase + (size_t)(j0 + srow) * 64 + ssc * 8, &Ks[buf][wid * 512]);
    gload_lds16(vbase + (size_t)srow * 2048 + j0 + ssc * 8, &Vs[buf][wid * 512]);
  };

  stage(0, 0);
  __syncthreads();

  for (int kt = 0; kt < 32; ++kt) {
    const int cur = kt & 1;
    if (kt < 31) stage(cur ^ 1, (kt + 1) * 64);   // prefetch next tile under compute

    // ---- S^T = K Q^T: A = K-frag (rows=keys), B = Q-frag (cols=q) ----
    f32x16 sa0, sa1;
#pragma unroll
    for (int r = 0; r < 16; ++r) { sa0[r] = 0.f; sa1[r] = 0.f; }
    __builtin_amdgcn_s_setprio(1);
#pragma unroll
    for (int dd = 0; dd < 4; ++dd) {
      bf16x8 k0 = *(const bf16x8*)(&Ks[cur][r31 * 64 + (((dd * 2 + hi) ^ lsw) << 3)]);
      bf16x8 k1 = *(const bf16x8*)(&Ks[cur][(32 + r31) * 64 + (((dd * 2 + hi) ^ lsw) << 3)]);
      sa0 = __builtin_amdgcn_mfma_f32_32x32x16_bf16(k0, qf[dd], sa0, 0, 0, 0);
      sa1 = __builtin_amdgcn_mfma_f32_32x32x16_bf16(k1, qf[dd], sa1, 0, 0, 0);
    }
    __builtin_amdgcn_s_setprio(0);

    // ---- per-q-row tile max (local regs + one cross-half combine) ----
    float pmax = sa0[0];
#pragma unroll
    for (int r = 1; r < 16; ++r) pmax = fmaxf(pmax, sa0[r]);
#pragma unroll
    for (int r = 0; r < 16; ++r) pmax = fmaxf(pmax, sa1[r]);
    pmax = fmaxf(pmax, __shfl_xor(pmax, 32, 64));

    // ---- defer-max: rescale only when some row's max grew past THR ----
    if (!__all(pmax - m <= THRR)) {
      float mn = fmaxf(m, pmax);
      float corr = __builtin_amdgcn_exp2f((m - mn) * EXPC);
      m = mn;
      lsum *= corr;
#pragma unroll
      for (int r = 0; r < 16; ++r) {
        int qrow = (r & 3) + 8 * (r >> 2) + 4 * hi;
        float cr = __shfl(corr, qrow, 64);   // corr lives at lane q (=q-row index)
        o0[r] *= cr; o1[r] *= cr;
      }
    }

    // ---- P = exp2((s - m)*EXPC), partial row-sum ----
    const float mc = m * EXPC;
    float p[2][16];
    float rs = 0.f;
#pragma unroll
    for (int r = 0; r < 16; ++r) {
      p[0][r] = __builtin_amdgcn_exp2f(fmaf(sa0[r], EXPC, -mc));
      p[1][r] = __builtin_amdgcn_exp2f(fmaf(sa1[r], EXPC, -mc));
      rs += p[0][r] + p[1][r];
    }
    lsum += rs;

    // ---- build PV A-frags in-register: pack pairs + permlane32_swap ----
    // frag kk = kb*2+ks covers keys kb*32 + ks*16 + hi*8 + j
    unsigned f[4][4];
#pragma unroll
    for (int kb2 = 0; kb2 < 2; ++kb2) {
#pragma unroll
      for (int ks = 0; ks < 2; ++ks) {
        unsigned a0 = pk2(p[kb2][ks * 8 + 0], p[kb2][ks * 8 + 1]);
        unsigned a1 = pk2(p[kb2][ks * 8 + 2], p[kb2][ks * 8 + 3]);
        unsigned b0 = pk2(p[kb2][ks * 8 + 4], p[kb2][ks * 8 + 5]);
        unsigned b1 = pk2(p[kb2][ks * 8 + 6], p[kb2][ks * 8 + 7]);
        asm("v_permlane32_swap_b32 %0, %1" : "+v"(a0), "+v"(b0));
        asm("v_permlane32_swap_b32 %0, %1" : "+v"(a1), "+v"(b1));
        f[kb2 * 2 + ks][0] = a0; f[kb2 * 2 + ks][1] = a1;
        f[kb2 * 2 + ks][2] = b0; f[kb2 * 2 + ks][3] = b1;
      }
    }

    // ---- O += P V: B-frag = V[key][d] from Vs[d][key] rows (b128, swizzled) ----
    __builtin_amdgcn_s_setprio(1);
#pragma unroll
    for (int kk = 0; kk < 4; ++kk) {
      u32x4 fw = {f[kk][0], f[kk][1], f[kk][2], f[kk][3]};
      bf16x8 pa = __builtin_bit_cast(bf16x8, fw);
      bf16x8 v0 = *(const bf16x8*)(&Vs[cur][r31 * 64 + (((kk * 2 + hi) ^ lsw) << 3)]);
      bf16x8 v1 = *(const bf16x8*)(&Vs[cur][(32 + r31) * 64 + (((kk * 2 + hi) ^ lsw) << 3)]);
      o0 = __builtin_amdgcn_mfma_f32_32x32x16_bf16(pa, v0, o0, 0, 0, 0);
      o1 = __builtin_amdgcn_mfma_f32_32x32x16_bf16(pa, v1, o1, 0, 0, 0);
    }
    __builtin_amdgcn_s_setprio(0);

    __syncthreads();  // prefetch drained (hidden under compute) + buffer swap
  }

  // ---- epilogue: combine halves, normalize, store ----
  lsum += __shfl_xor(lsum, 32, 64);
  float inv = 1.0f / lsum;
  const int b = bh >> 4, h = bh & 15;
  __bf16* abase = ao + ((size_t)b * 2048 + nbase) * 1024 + h * 64 + r31;
#pragma unroll
  for (int r = 0; r < 16; ++r) {
    int qrow = (r & 3) + 8 * (r >> 2) + 4 * hi;
    float ir = __shfl(inv, qrow, 64);
    abase[(size_t)qrow * 1024] = (__bf16)(o0[r] * ir);
    abase[(size_t)qrow * 1024 + 32] = (__bf16)(o1[r] * ir);
  }
}

extern "C" void kernel_launch(void* const* d_in, const int* in_sizes, int n_in,
                              void* d_out, int out_size, void* d_ws, size_t ws_size,
                              hipStream_t stream) {
  (void)in_sizes; (void)n_in; (void)out_size; (void)ws_size;
  const float* x = (const float*)d_in[0];      // [4,2048,1024]
  const float* w_qkv = (const float*)d_in[1];  // [1024,3072]
  const float* w_out = (const float*)d_in[2];  // [1024,1024]
  float* out = (float*)d_out;                  // [4,2048,1024]

  char* p = (char*)d_ws;
  __bf16* xb    = (__bf16*)p; p += (size_t)8192 * 1024 * 2;  // x bf16 [8192][1024]
  __bf16* wqkvT = (__bf16*)p; p += (size_t)3072 * 1024 * 2;  // w_qkv^T [3072][1024]
  __bf16* woutT = (__bf16*)p; p += (size_t)1024 * 1024 * 2;  // w_out^T [1024][1024]
  __bf16* qb    = (__bf16*)p; p += (size_t)64 * 2048 * 64 * 2;  // [bh][n][d]
  __bf16* kb    = (__bf16*)p; p += (size_t)64 * 2048 * 64 * 2;  // [bh][n][d]
  __bf16* vb    = (__bf16*)p; p += (size_t)64 * 64 * 2048 * 2;  // [bh][d][n]
  __bf16* ao    = (__bf16*)p; p += (size_t)8192 * 1024 * 2;     // [b*n][h*d]

  k_cvt<<<8192, 256, 0, stream>>>(x, xb, 2097152);
  k_tcvt<<<dim3(96, 32), dim3(32, 8), 0, stream>>>(w_qkv, wqkvT, 3072, 1024);
  k_tcvt<<<dim3(32, 32), dim3(32, 8), 0, stream>>>(w_out, woutT, 1024, 1024);
  k_gemm_qkv<<<dim3(64, 24), 256, 0, stream>>>(xb, wqkvT, qb, kb, vb);
  k_attn<<<dim3(512), dim3(512), 0, stream>>>(qb, kb, vb, ao);
  k_gemm_out<<<dim3(64, 8), 256, 0, stream>>>(ao, woutT, out);
}

// Round 4
// 216.960 us; speedup vs baseline: 1.7863x; 1.0234x over previous
//
#include <hip/hip_runtime.h>
#include <hip/hip_bf16.h>
#include <stdint.h>

// MHSA fused: B=4, N=2048, D=1024, H=16, Dh=64
// Pipeline: cvt(x) / tcvt(w_qkv) / tcvt(w_out) -> gemm_qkv -> flash attn -> gemm_out

typedef __attribute__((ext_vector_type(8))) __bf16 bf16x8;
typedef __attribute__((ext_vector_type(4))) __bf16 bf16x4;
typedef __attribute__((ext_vector_type(4))) float f32x4;
typedef __attribute__((ext_vector_type(16))) float f32x16;
typedef __attribute__((ext_vector_type(4))) unsigned int u32x4;

// 0.125 (head-dim scale) * log2(e)
#define EXPC 0.18033688011112042f
// defer-max threshold in raw-score units (0.125*64 = 8 nats -> p <= e^8 fits bf16 easily)
#define THRR 64.0f

static __device__ __forceinline__ void gload_lds16(const void* g, void* s) {
  // dest = wave-uniform LDS base + lane*16B (HW behavior), 16B per lane
  __builtin_amdgcn_global_load_lds(
      (__attribute__((address_space(1))) unsigned int*)g,
      (__attribute__((address_space(3))) unsigned int*)s, 16, 0, 0);
}

static __device__ __forceinline__ unsigned pk2(float lo, float hi) {
  unsigned short a = __builtin_bit_cast(unsigned short, (__bf16)lo);
  unsigned short b = __builtin_bit_cast(unsigned short, (__bf16)hi);
  return (unsigned)a | ((unsigned)b << 16);
}

// ---------------- f32 -> bf16 flat convert (vectorized) ----------------
__global__ void k_cvt(const float* __restrict__ src, __bf16* __restrict__ dst, int n4) {
  int i = blockIdx.x * blockDim.x + threadIdx.x;
  if (i >= n4) return;
  float4 v = reinterpret_cast<const float4*>(src)[i];
  bf16x4 o = { (__bf16)v.x, (__bf16)v.y, (__bf16)v.z, (__bf16)v.w };
  *reinterpret_cast<bf16x4*>(dst + (size_t)i * 4) = o;
}

// ---------------- transpose + convert: dst[c][r] = src[r][c], src is Hs x W ----
__global__ void k_tcvt(const float* __restrict__ src, __bf16* __restrict__ dst, int W, int Hs) {
  __shared__ float tile[32][33];
  int tx = threadIdx.x, ty = threadIdx.y;  // 32 x 8
  int x = blockIdx.x * 32 + tx;
  int y0 = blockIdx.y * 32;
  for (int j = ty; j < 32; j += 8) tile[j][tx] = src[(size_t)(y0 + j) * W + x];
  __syncthreads();
  int xo = y0 + tx;
  int yo = blockIdx.x * 32;
  for (int j = ty; j < 32; j += 8) dst[(size_t)(yo + j) * Hs + xo] = (__bf16)tile[tx][j];
}

// ---------------- m97-structure GEMM core: C(128x128) = A[M][K] * BT[N][K]^T ----
// 4 waves, each 64x64 via 4x4 frags of 16x16x32 bf16. BK=32.
static __device__ __forceinline__ void gemm_core(
    const __bf16* __restrict__ A, const __bf16* __restrict__ BT, int K,
    int m0, int n0, f32x4 acc[4][4], __bf16* As, __bf16* Bs) {
  const int tid = threadIdx.x;
  const int lane = tid & 63, w = tid >> 6;
  const int fr = lane & 15, fq = lane >> 4;
  const int srow = lane >> 2, scol = (lane & 3) * 8;  // 64 lanes x 16B = 16 rows of 32 bf16
  const int wr = (w >> 1) * 64, wc = (w & 1) * 64;
#pragma unroll
  for (int mi = 0; mi < 4; ++mi)
#pragma unroll
    for (int nj = 0; nj < 4; ++nj) acc[mi][nj] = (f32x4){0.f, 0.f, 0.f, 0.f};

  for (int ko = 0; ko < K; ko += 32) {
#pragma unroll
    for (int i = 0; i < 2; ++i) {
      int rb = w * 32 + i * 16;
      gload_lds16(A + (size_t)(m0 + rb + srow) * K + ko + scol, As + rb * 32);
      gload_lds16(BT + (size_t)(n0 + rb + srow) * K + ko + scol, Bs + rb * 32);
    }
    __syncthreads();
    bf16x8 af[4], bfv[4];
#pragma unroll
    for (int mi = 0; mi < 4; ++mi)
      af[mi] = *(const bf16x8*)(As + (wr + mi * 16 + fr) * 32 + fq * 8);
#pragma unroll
    for (int nj = 0; nj < 4; ++nj)
      bfv[nj] = *(const bf16x8*)(Bs + (wc + nj * 16 + fr) * 32 + fq * 8);
#pragma unroll
    for (int mi = 0; mi < 4; ++mi)
#pragma unroll
      for (int nj = 0; nj < 4; ++nj)
        acc[mi][nj] = __builtin_amdgcn_mfma_f32_16x16x32_bf16(af[mi], bfv[nj], acc[mi][nj], 0, 0, 0);
    __syncthreads();
  }
}

// C cols 0..3071: [q | k | v]. q,k -> [bh][n][64]; v -> transposed [bh][64][n]
__global__ __launch_bounds__(256) void k_gemm_qkv(
    const __bf16* __restrict__ A, const __bf16* __restrict__ BT,
    __bf16* __restrict__ qb, __bf16* __restrict__ kb, __bf16* __restrict__ vb) {
  __shared__ __align__(16) __bf16 As[128 * 32];
  __shared__ __align__(16) __bf16 Bs[128 * 32];
  f32x4 acc[4][4];
  int m0 = blockIdx.x * 128, n0 = blockIdx.y * 128;
  gemm_core(A, BT, 1024, m0, n0, acc, As, Bs);
  const int lane = threadIdx.x & 63, w = threadIdx.x >> 6;
  const int fr = lane & 15, fq = lane >> 4;
  const int wr = (w >> 1) * 64, wc = (w & 1) * 64;
  const int which = n0 >> 10;  // 128-col tile never crosses a q/k/v boundary
#pragma unroll
  for (int mi = 0; mi < 4; ++mi) {
#pragma unroll
    for (int nj = 0; nj < 4; ++nj) {
      int row = m0 + wr + mi * 16 + fq * 4;          // token index (4 consecutive)
      int col = n0 + wc + nj * 16 + fr;              // qkv column
      int rem = col & 1023, h = rem >> 6, d = rem & 63;
      int bb = row >> 11, n = row & 2047;            // row..row+3 stay in one b
      int bh = bb * 16 + h;
      if (which == 2) {
        bf16x4 pk = { (__bf16)acc[mi][nj][0], (__bf16)acc[mi][nj][1],
                      (__bf16)acc[mi][nj][2], (__bf16)acc[mi][nj][3] };
        *reinterpret_cast<bf16x4*>(vb + ((size_t)bh * 64 + d) * 2048 + n) = pk;
      } else {
        __bf16* dst = (which == 0) ? qb : kb;
#pragma unroll
        for (int j = 0; j < 4; ++j)
          dst[((size_t)bh * 2048 + (n + j)) * 64 + d] = (__bf16)acc[mi][nj][j];
      }
    }
  }
}

__global__ __launch_bounds__(256) void k_gemm_out(
    const __bf16* __restrict__ A, const __bf16* __restrict__ BT, float* __restrict__ C) {
  __shared__ __align__(16) __bf16 As[128 * 32];
  __shared__ __align__(16) __bf16 Bs[128 * 32];
  f32x4 acc[4][4];
  int m0 = blockIdx.x * 128, n0 = blockIdx.y * 128;
  gemm_core(A, BT, 1024, m0, n0, acc, As, Bs);
  const int lane = threadIdx.x & 63, w = threadIdx.x >> 6;
  const int fr = lane & 15, fq = lane >> 4;
  const int wr = (w >> 1) * 64, wc = (w & 1) * 64;
#pragma unroll
  for (int mi = 0; mi < 4; ++mi)
#pragma unroll
    for (int nj = 0; nj < 4; ++nj)
#pragma unroll
      for (int j = 0; j < 4; ++j)
        C[(size_t)(m0 + wr + mi * 16 + fq * 4 + j) * 1024 + n0 + wc + nj * 16 + fr] =
            acc[mi][nj][j];
}

// ---------------- flash attention, 4-warp 32x32 swapped structure ----------------
// Block = (b,h) x 128 q-rows; 4 warps x 32 q-rows. KVBLK=64, D=64. Grid 64bh x 16qblk.
// (4-warp blocks: ~3 blocks/CU resident; independent blocks drift out of phase so
//  one block's softmax VALU overlaps another's MFMA burst.)
// Swapped QK^T: S^T = mfma(K, Q) -> lane (q=l&31) holds P for 32 keys (16 per half-lane,
// keys = kb*32 + crow(r,hi), crow = (r&3)+8*(r>>2)+4*hi). Softmax fully in-register,
// max/sum via depth-5 trees (no 31-deep serial chains).
// P -> PV A-frags via bf16 pack + v_permlane32_swap (no LDS roundtrip).
// K/V LDS: [row][64] bf16 rows (128B), 16B-chunk XOR swizzle c ^= (row&7) ^ ((row>>3)&3)
// -> conflict-free b128 reads; staged via pre-swizzled-source global_load_lds.
__global__ __launch_bounds__(256, 2) void k_attn(
    const __bf16* __restrict__ qb, const __bf16* __restrict__ kb,
    const __bf16* __restrict__ vb, __bf16* __restrict__ ao) {
  __shared__ __align__(16) __bf16 Ks[2][64 * 64];   // [key][d], swizzled
  __shared__ __align__(16) __bf16 Vs[2][64 * 64];   // [d][key], swizzled (vb pre-transposed)
  const int tid = threadIdx.x, lane = tid & 63, wid = tid >> 6;
  const int r31 = lane & 31, hi = lane >> 5;
  const int lsw = (lane & 7) ^ ((lane >> 3) & 3);   // read-side chunk swizzle
  const int bh = blockIdx.x & 63, qblk = blockIdx.x >> 6;  // same-bh blocks land on one XCD
  const __bf16* kbase = kb + (size_t)bh * 2048 * 64;
  const __bf16* vbase = vb + (size_t)bh * 64 * 2048;

  // Q resident in registers: B-operand frag = Q[q=l&31][d = dd*16 + hi*8 + j]
  const int nbase = qblk * 128 + wid * 32;
  const __bf16* qptr = qb + ((size_t)bh * 2048 + nbase + r31) * 64;
  bf16x8 qf[4];
#pragma unroll
  for (int dd = 0; dd < 4; ++dd)
    qf[dd] = *(const bf16x8*)(qptr + dd * 16 + hi * 8);

  f32x16 o0, o1;   // O accum: rows q=crow(r,hi), cols d = dblk*32 + (l&31)
#pragma unroll
  for (int r = 0; r < 16; ++r) { o0[r] = 0.f; o1[r] = 0.f; }
  float m = -1e30f, lsum = 0.f;  // per q-row (q = l&31); lsum = own-half partial

  // staging: 256 threads x 2 passes; pass p covers rows p*32..p*32+31 (8 rows/wave/pass)
  auto stage = [&](int buf, int j0) {
#pragma unroll
    for (int p2 = 0; p2 < 2; ++p2) {
      int row = p2 * 32 + (tid >> 3);
      int sc = (tid & 7) ^ (row & 7) ^ ((row >> 3) & 3);  // pre-swizzled source chunk
      int dst = p2 * 2048 + wid * 512;                    // wave-uniform LDS base (elems)
      gload_lds16(kbase + (size_t)(j0 + row) * 64 + sc * 8, &Ks[buf][dst]);
      gload_lds16(vbase + (size_t)row * 2048 + j0 + sc * 8, &Vs[buf][dst]);
    }
  };

  stage(0, 0);
  __syncthreads();

  for (int kt = 0; kt < 32; ++kt) {
    const int cur = kt & 1;
    if (kt < 31) stage(cur ^ 1, (kt + 1) * 64);   // prefetch next tile under compute

    // ---- S^T = K Q^T: A = K-frag (rows=keys), B = Q-frag (cols=q) ----
    f32x16 sa0, sa1;
#pragma unroll
    for (int r = 0; r < 16; ++r) { sa0[r] = 0.f; sa1[r] = 0.f; }
    __builtin_amdgcn_s_setprio(1);
#pragma unroll
    for (int dd = 0; dd < 4; ++dd) {
      bf16x8 k0 = *(const bf16x8*)(&Ks[cur][r31 * 64 + (((dd * 2 + hi) ^ lsw) << 3)]);
      bf16x8 k1 = *(const bf16x8*)(&Ks[cur][(32 + r31) * 64 + (((dd * 2 + hi) ^ lsw) << 3)]);
      sa0 = __builtin_amdgcn_mfma_f32_32x32x16_bf16(k0, qf[dd], sa0, 0, 0, 0);
      sa1 = __builtin_amdgcn_mfma_f32_32x32x16_bf16(k1, qf[dd], sa1, 0, 0, 0);
    }
    __builtin_amdgcn_s_setprio(0);

    // ---- per-q-row tile max: depth-5 tree + one cross-half combine ----
    float mx[8];
#pragma unroll
    for (int r = 0; r < 8; ++r)
      mx[r] = fmaxf(fmaxf(sa0[2 * r], sa0[2 * r + 1]), fmaxf(sa1[2 * r], sa1[2 * r + 1]));
#pragma unroll
    for (int s = 4; s > 0; s >>= 1)
#pragma unroll
      for (int r = 0; r < s; ++r) mx[r] = fmaxf(mx[r], mx[r + s]);
    float pmax = fmaxf(mx[0], __shfl_xor(mx[0], 32, 64));

    // ---- defer-max: rescale only when some row's max grew past THR ----
    if (!__all(pmax - m <= THRR)) {
      float mn = fmaxf(m, pmax);
      float corr = __builtin_amdgcn_exp2f((m - mn) * EXPC);
      m = mn;
      lsum *= corr;
#pragma unroll
      for (int r = 0; r < 16; ++r) {
        int qrow = (r & 3) + 8 * (r >> 2) + 4 * hi;
        float cr = __shfl(corr, qrow, 64);   // corr lives at lane q (=q-row index)
        o0[r] *= cr; o1[r] *= cr;
      }
    }

    // ---- P = exp2((s - m)*EXPC), partial row-sum (tree) ----
    const float mc = m * EXPC;
    float p[2][16];
#pragma unroll
    for (int r = 0; r < 16; ++r) {
      p[0][r] = __builtin_amdgcn_exp2f(fmaf(sa0[r], EXPC, -mc));
      p[1][r] = __builtin_amdgcn_exp2f(fmaf(sa1[r], EXPC, -mc));
    }
    float ss[8];
#pragma unroll
    for (int r = 0; r < 8; ++r)
      ss[r] = (p[0][2 * r] + p[0][2 * r + 1]) + (p[1][2 * r] + p[1][2 * r + 1]);
#pragma unroll
    for (int s = 4; s > 0; s >>= 1)
#pragma unroll
      for (int r = 0; r < s; ++r) ss[r] += ss[r + s];
    lsum += ss[0];

    // ---- build PV A-frags in-register: pack pairs + permlane32_swap ----
    // frag kk = kb*2+ks covers keys kb*32 + ks*16 + hi*8 + j
    unsigned f[4][4];
#pragma unroll
    for (int kb2 = 0; kb2 < 2; ++kb2) {
#pragma unroll
      for (int ks = 0; ks < 2; ++ks) {
        unsigned a0 = pk2(p[kb2][ks * 8 + 0], p[kb2][ks * 8 + 1]);
        unsigned a1 = pk2(p[kb2][ks * 8 + 2], p[kb2][ks * 8 + 3]);
        unsigned b0 = pk2(p[kb2][ks * 8 + 4], p[kb2][ks * 8 + 5]);
        unsigned b1 = pk2(p[kb2][ks * 8 + 6], p[kb2][ks * 8 + 7]);
        asm("v_permlane32_swap_b32 %0, %1" : "+v"(a0), "+v"(b0));
        asm("v_permlane32_swap_b32 %0, %1" : "+v"(a1), "+v"(b1));
        f[kb2 * 2 + ks][0] = a0; f[kb2 * 2 + ks][1] = a1;
        f[kb2 * 2 + ks][2] = b0; f[kb2 * 2 + ks][3] = b1;
      }
    }

    // ---- O += P V: B-frag = V[key][d] from Vs[d][key] rows (b128, swizzled) ----
    __builtin_amdgcn_s_setprio(1);
#pragma unroll
    for (int kk = 0; kk < 4; ++kk) {
      u32x4 fw = {f[kk][0], f[kk][1], f[kk][2], f[kk][3]};
      bf16x8 pa = __builtin_bit_cast(bf16x8, fw);
      bf16x8 v0 = *(const bf16x8*)(&Vs[cur][r31 * 64 + (((kk * 2 + hi) ^ lsw) << 3)]);
      bf16x8 v1 = *(const bf16x8*)(&Vs[cur][(32 + r31) * 64 + (((kk * 2 + hi) ^ lsw) << 3)]);
      o0 = __builtin_amdgcn_mfma_f32_32x32x16_bf16(pa, v0, o0, 0, 0, 0);
      o1 = __builtin_amdgcn_mfma_f32_32x32x16_bf16(pa, v1, o1, 0, 0, 0);
    }
    __builtin_amdgcn_s_setprio(0);

    __syncthreads();  // prefetch drained (hidden under compute) + buffer swap
  }

  // ---- epilogue: combine halves, normalize, store ----
  lsum += __shfl_xor(lsum, 32, 64);
  float inv = 1.0f / lsum;
  const int b = bh >> 4, h = bh & 15;
  __bf16* abase = ao + ((size_t)b * 2048 + nbase) * 1024 + h * 64 + r31;
#pragma unroll
  for (int r = 0; r < 16; ++r) {
    int qrow = (r & 3) + 8 * (r >> 2) + 4 * hi;
    float ir = __shfl(inv, qrow, 64);
    abase[(size_t)qrow * 1024] = (__bf16)(o0[r] * ir);
    abase[(size_t)qrow * 1024 + 32] = (__bf16)(o1[r] * ir);
  }
}

extern "C" void kernel_launch(void* const* d_in, const int* in_sizes, int n_in,
                              void* d_out, int out_size, void* d_ws, size_t ws_size,
                              hipStream_t stream) {
  (void)in_sizes; (void)n_in; (void)out_size; (void)ws_size;
  const float* x = (const float*)d_in[0];      // [4,2048,1024]
  const float* w_qkv = (const float*)d_in[1];  // [1024,3072]
  const float* w_out = (const float*)d_in[2];  // [1024,1024]
  float* out = (float*)d_out;                  // [4,2048,1024]

  char* p = (char*)d_ws;
  __bf16* xb    = (__bf16*)p; p += (size_t)8192 * 1024 * 2;  // x bf16 [8192][1024]
  __bf16* wqkvT = (__bf16*)p; p += (size_t)3072 * 1024 * 2;  // w_qkv^T [3072][1024]
  __bf16* woutT = (__bf16*)p; p += (size_t)1024 * 1024 * 2;  // w_out^T [1024][1024]
  __bf16* qb    = (__bf16*)p; p += (size_t)64 * 2048 * 64 * 2;  // [bh][n][d]
  __bf16* kb    = (__bf16*)p; p += (size_t)64 * 2048 * 64 * 2;  // [bh][n][d]
  __bf16* vb    = (__bf16*)p; p += (size_t)64 * 64 * 2048 * 2;  // [bh][d][n]
  __bf16* ao    = (__bf16*)p; p += (size_t)8192 * 1024 * 2;     // [b*n][h*d]

  k_cvt<<<8192, 256, 0, stream>>>(x, xb, 2097152);
  k_tcvt<<<dim3(96, 32), dim3(32, 8), 0, stream>>>(w_qkv, wqkvT, 3072, 1024);
  k_tcvt<<<dim3(32, 32), dim3(32, 8), 0, stream>>>(w_out, woutT, 1024, 1024);
  k_gemm_qkv<<<dim3(64, 24), 256, 0, stream>>>(xb, wqkvT, qb, kb, vb);
  k_attn<<<dim3(1024), dim3(256), 0, stream>>>(qb, kb, vb, ao);
  k_gemm_out<<<dim3(64, 8), 256, 0, stream>>>(ao, woutT, out);
}

// Round 7
// 215.249 us; speedup vs baseline: 1.8005x; 1.0079x over previous
//
#include <hip/hip_runtime.h>
#include <hip/hip_bf16.h>
#include <stdint.h>

// MHSA fused: B=4, N=2048, D=1024, H=16, Dh=64
// Pipeline: cvt(x) / tcvt(w_qkv) / tcvt(w_out) -> gemm_qkv -> flash attn -> gemm_out

typedef __attribute__((ext_vector_type(8))) __bf16 bf16x8;
typedef __attribute__((ext_vector_type(4))) __bf16 bf16x4;
typedef __attribute__((ext_vector_type(4))) float f32x4;
typedef __attribute__((ext_vector_type(16))) float f32x16;
typedef __attribute__((ext_vector_type(4))) unsigned int u32x4;

// 0.125 (head-dim scale) * log2(e)
#define EXPC 0.18033688011112042f
// defer-max threshold in raw-score units (0.125*64 = 8 nats -> p <= e^8 fits bf16 easily)
#define THRR 64.0f

static __device__ __forceinline__ void gload_lds16(const void* g, void* s) {
  // dest = wave-uniform LDS base + lane*16B (HW behavior), 16B per lane
  __builtin_amdgcn_global_load_lds(
      (__attribute__((address_space(1))) unsigned int*)g,
      (__attribute__((address_space(3))) unsigned int*)s, 16, 0, 0);
}

// software bf16 pair-pack (validated rounds 3/4)
static __device__ __forceinline__ unsigned pk2(float lo, float hi) {
  unsigned short a = __builtin_bit_cast(unsigned short, (__bf16)lo);
  unsigned short b = __builtin_bit_cast(unsigned short, (__bf16)hi);
  return (unsigned)a | ((unsigned)b << 16);
}

// ---------------- f32 -> bf16 flat convert (vectorized) ----------------
__global__ void k_cvt(const float* __restrict__ src, __bf16* __restrict__ dst, int n4) {
  int i = blockIdx.x * blockDim.x + threadIdx.x;
  if (i >= n4) return;
  float4 v = reinterpret_cast<const float4*>(src)[i];
  bf16x4 o = { (__bf16)v.x, (__bf16)v.y, (__bf16)v.z, (__bf16)v.w };
  *reinterpret_cast<bf16x4*>(dst + (size_t)i * 4) = o;
}

// ---------------- transpose + convert: dst[c][r] = src[r][c], src is Hs x W ----
__global__ void k_tcvt(const float* __restrict__ src, __bf16* __restrict__ dst, int W, int Hs) {
  __shared__ float tile[32][33];
  int tx = threadIdx.x, ty = threadIdx.y;  // 32 x 8
  int x = blockIdx.x * 32 + tx;
  int y0 = blockIdx.y * 32;
  for (int j = ty; j < 32; j += 8) tile[j][tx] = src[(size_t)(y0 + j) * W + x];
  __syncthreads();
  int xo = y0 + tx;
  int yo = blockIdx.x * 32;
  for (int j = ty; j < 32; j += 8) dst[(size_t)(yo + j) * Hs + xo] = (__bf16)tile[tx][j];
}

// ---------------- m97-structure GEMM core: C(128x128) = A[M][K] * BT[N][K]^T ----
// 4 waves, each 64x64 via 4x4 frags of 16x16x32 bf16. BK=32.
static __device__ __forceinline__ void gemm_core(
    const __bf16* __restrict__ A, const __bf16* __restrict__ BT, int K,
    int m0, int n0, f32x4 acc[4][4], __bf16* As, __bf16* Bs) {
  const int tid = threadIdx.x;
  const int lane = tid & 63, w = tid >> 6;
  const int fr = lane & 15, fq = lane >> 4;
  const int srow = lane >> 2, scol = (lane & 3) * 8;  // 64 lanes x 16B = 16 rows of 32 bf16
  const int wr = (w >> 1) * 64, wc = (w & 1) * 64;
#pragma unroll
  for (int mi = 0; mi < 4; ++mi)
#pragma unroll
    for (int nj = 0; nj < 4; ++nj) acc[mi][nj] = (f32x4){0.f, 0.f, 0.f, 0.f};

  for (int ko = 0; ko < K; ko += 32) {
#pragma unroll
    for (int i = 0; i < 2; ++i) {
      int rb = w * 32 + i * 16;
      gload_lds16(A + (size_t)(m0 + rb + srow) * K + ko + scol, As + rb * 32);
      gload_lds16(BT + (size_t)(n0 + rb + srow) * K + ko + scol, Bs + rb * 32);
    }
    __syncthreads();
    bf16x8 af[4], bfv[4];
#pragma unroll
    for (int mi = 0; mi < 4; ++mi)
      af[mi] = *(const bf16x8*)(As + (wr + mi * 16 + fr) * 32 + fq * 8);
#pragma unroll
    for (int nj = 0; nj < 4; ++nj)
      bfv[nj] = *(const bf16x8*)(Bs + (wc + nj * 16 + fr) * 32 + fq * 8);
#pragma unroll
    for (int mi = 0; mi < 4; ++mi)
#pragma unroll
      for (int nj = 0; nj < 4; ++nj)
        acc[mi][nj] = __builtin_amdgcn_mfma_f32_16x16x32_bf16(af[mi], bfv[nj], acc[mi][nj], 0, 0, 0);
    __syncthreads();
  }
}

// C cols 0..3071: [q | k | v]. q,k -> [bh][n][64]; v -> transposed [bh][64][n]
__global__ __launch_bounds__(256) void k_gemm_qkv(
    const __bf16* __restrict__ A, const __bf16* __restrict__ BT,
    __bf16* __restrict__ qb, __bf16* __restrict__ kb, __bf16* __restrict__ vb) {
  __shared__ __align__(16) __bf16 As[128 * 32];
  __shared__ __align__(16) __bf16 Bs[128 * 32];
  f32x4 acc[4][4];
  int m0 = blockIdx.x * 128, n0 = blockIdx.y * 128;
  gemm_core(A, BT, 1024, m0, n0, acc, As, Bs);
  const int lane = threadIdx.x & 63, w = threadIdx.x >> 6;
  const int fr = lane & 15, fq = lane >> 4;
  const int wr = (w >> 1) * 64, wc = (w & 1) * 64;
  const int which = n0 >> 10;  // 128-col tile never crosses a q/k/v boundary
#pragma unroll
  for (int mi = 0; mi < 4; ++mi) {
#pragma unroll
    for (int nj = 0; nj < 4; ++nj) {
      int row = m0 + wr + mi * 16 + fq * 4;          // token index (4 consecutive)
      int col = n0 + wc + nj * 16 + fr;              // qkv column
      int rem = col & 1023, h = rem >> 6, d = rem & 63;
      int bb = row >> 11, n = row & 2047;            // row..row+3 stay in one b
      int bh = bb * 16 + h;
      if (which == 2) {
        bf16x4 pk = { (__bf16)acc[mi][nj][0], (__bf16)acc[mi][nj][1],
                      (__bf16)acc[mi][nj][2], (__bf16)acc[mi][nj][3] };
        *reinterpret_cast<bf16x4*>(vb + ((size_t)bh * 64 + d) * 2048 + n) = pk;
      } else {
        __bf16* dst = (which == 0) ? qb : kb;
#pragma unroll
        for (int j = 0; j < 4; ++j)
          dst[((size_t)bh * 2048 + (n + j)) * 64 + d] = (__bf16)acc[mi][nj][j];
      }
    }
  }
}

__global__ __launch_bounds__(256) void k_gemm_out(
    const __bf16* __restrict__ A, const __bf16* __restrict__ BT, float* __restrict__ C) {
  __shared__ __align__(16) __bf16 As[128 * 32];
  __shared__ __align__(16) __bf16 Bs[128 * 32];
  f32x4 acc[4][4];
  int m0 = blockIdx.x * 128, n0 = blockIdx.y * 128;
  gemm_core(A, BT, 1024, m0, n0, acc, As, Bs);
  const int lane = threadIdx.x & 63, w = threadIdx.x >> 6;
  const int fr = lane & 15, fq = lane >> 4;
  const int wr = (w >> 1) * 64, wc = (w & 1) * 64;
#pragma unroll
  for (int mi = 0; mi < 4; ++mi)
#pragma unroll
    for (int nj = 0; nj < 4; ++nj)
#pragma unroll
      for (int j = 0; j < 4; ++j)
        C[(size_t)(m0 + wr + mi * 16 + fq * 4 + j) * 1024 + n0 + wc + nj * 16 + fr] =
            acc[mi][nj][j];
}

// ---------------- flash attention, 4-warp 32x32 swapped structure ----------------
// Block = (b,h) x 128 q-rows; 4 warps x 32 q-rows. KVBLK=64, D=64. Grid 64bh x 16qblk.
// Swapped QK^T: S^T = mfma(K, Q) -> lane (q=l&31) holds P for 32 keys (16 per half-lane,
// keys = kb*32 + crow(r,hi), crow = (r&3)+8*(r>>2)+4*hi). Softmax fully in-register,
// max via depth-5 tree; exp packed immediately via software pk2 (no f32 P array).
// Scalar cross-half combines use __shfl_xor(...,32) — NOT same-value permlane asm
// (regalloc coalesces the two identical "+v" operands into one register, degenerating
// the swap; this was the round-5/6 correctness bug).
// P -> PV A-frags via packed words + v_permlane32_swap (distinct values — safe, validated).
// K/V LDS: [row][64] bf16 rows (128B), 16B-chunk XOR swizzle c ^= (row&7) ^ ((row>>3)&3)
// -> conflict-free b128 reads; staged via pre-swizzled-source global_load_lds.
__global__ __launch_bounds__(256, 3) void k_attn(
    const __bf16* __restrict__ qb, const __bf16* __restrict__ kb,
    const __bf16* __restrict__ vb, __bf16* __restrict__ ao) {
  __shared__ __align__(16) __bf16 Ks[2][64 * 64];   // [key][d], swizzled
  __shared__ __align__(16) __bf16 Vs[2][64 * 64];   // [d][key], swizzled (vb pre-transposed)
  const int tid = threadIdx.x, lane = tid & 63, wid = tid >> 6;
  const int r31 = lane & 31, hi = lane >> 5;
  const int lsw = (lane & 7) ^ ((lane >> 3) & 3);   // read-side chunk swizzle
  const int bh = blockIdx.x & 63, qblk = blockIdx.x >> 6;  // same-bh blocks land on one XCD
  const __bf16* kbase = kb + (size_t)bh * 2048 * 64;
  const __bf16* vbase = vb + (size_t)bh * 64 * 2048;

  // Q resident in registers: B-operand frag = Q[q=l&31][d = dd*16 + hi*8 + j]
  const int nbase = qblk * 128 + wid * 32;
  const __bf16* qptr = qb + ((size_t)bh * 2048 + nbase + r31) * 64;
  bf16x8 qf[4];
#pragma unroll
  for (int dd = 0; dd < 4; ++dd)
    qf[dd] = *(const bf16x8*)(qptr + dd * 16 + hi * 8);

  f32x16 o0, o1;   // O accum: rows q=crow(r,hi), cols d = dblk*32 + (l&31)
#pragma unroll
  for (int r = 0; r < 16; ++r) { o0[r] = 0.f; o1[r] = 0.f; }
  float m = -1e30f, lsum = 0.f;  // per q-row (q = l&31); lsum = own-half partial

  // staging: 256 threads x 2 passes; pass p covers rows p*32..p*32+31 (8 rows/wave/pass)
  auto stage = [&](int buf, int j0) {
#pragma unroll
    for (int p2 = 0; p2 < 2; ++p2) {
      int row = p2 * 32 + (tid >> 3);
      int sc = (tid & 7) ^ (row & 7) ^ ((row >> 3) & 3);  // pre-swizzled source chunk
      int dst = p2 * 2048 + wid * 512;                    // wave-uniform LDS base (elems)
      gload_lds16(kbase + (size_t)(j0 + row) * 64 + sc * 8, &Ks[buf][dst]);
      gload_lds16(vbase + (size_t)row * 2048 + j0 + sc * 8, &Vs[buf][dst]);
    }
  };

  stage(0, 0);
  __syncthreads();

  for (int kt = 0; kt < 32; ++kt) {
    const int cur = kt & 1;
    if (kt < 31) stage(cur ^ 1, (kt + 1) * 64);   // prefetch next tile under compute

    // ---- S^T = K Q^T: A = K-frag (rows=keys), B = Q-frag (cols=q) ----
    f32x16 sa0, sa1;
#pragma unroll
    for (int r = 0; r < 16; ++r) { sa0[r] = 0.f; sa1[r] = 0.f; }
    __builtin_amdgcn_s_setprio(1);
#pragma unroll
    for (int dd = 0; dd < 4; ++dd) {
      bf16x8 k0 = *(const bf16x8*)(&Ks[cur][r31 * 64 + (((dd * 2 + hi) ^ lsw) << 3)]);
      bf16x8 k1 = *(const bf16x8*)(&Ks[cur][(32 + r31) * 64 + (((dd * 2 + hi) ^ lsw) << 3)]);
      sa0 = __builtin_amdgcn_mfma_f32_32x32x16_bf16(k0, qf[dd], sa0, 0, 0, 0);
      sa1 = __builtin_amdgcn_mfma_f32_32x32x16_bf16(k1, qf[dd], sa1, 0, 0, 0);
    }
    __builtin_amdgcn_s_setprio(0);

    // ---- per-q-row tile max: depth-5 tree + cross-half combine (__shfl_xor) ----
    float mx[8];
#pragma unroll
    for (int r = 0; r < 8; ++r)
      mx[r] = fmaxf(fmaxf(fmaxf(sa0[2 * r], sa0[2 * r + 1]), sa1[2 * r]), sa1[2 * r + 1]);
#pragma unroll
    for (int s = 4; s > 0; s >>= 1)
#pragma unroll
      for (int r = 0; r < s; ++r) mx[r] = fmaxf(mx[r], mx[r + s]);
    float pmax = fmaxf(mx[0], __shfl_xor(mx[0], 32, 64));

    // ---- defer-max: rescale only when some row's max grew past THR ----
    if (!__all(pmax - m <= THRR)) {
      float mn = fmaxf(m, pmax);
      float corr = __builtin_amdgcn_exp2f((m - mn) * EXPC);
      m = mn;
      lsum *= corr;
#pragma unroll
      for (int r = 0; r < 16; ++r) {
        int qrow = (r & 3) + 8 * (r >> 2) + 4 * hi;
        float cr = __shfl(corr, qrow, 64);   // corr lives at lane q (=q-row index)
        o0[r] *= cr; o1[r] *= cr;
      }
    }

    // ---- P = exp2((s - m)*EXPC): pack pairs immediately (software pk2) ----
    const float mneg = -m * EXPC;
    float rs0 = 0.f, rs1 = 0.f, rs2 = 0.f, rs3 = 0.f;
    unsigned pw0[8], pw1[8];
#pragma unroll
    for (int r = 0; r < 8; ++r) {
      float e0 = __builtin_amdgcn_exp2f(fmaf(sa0[2 * r], EXPC, mneg));
      float e1 = __builtin_amdgcn_exp2f(fmaf(sa0[2 * r + 1], EXPC, mneg));
      float e2 = __builtin_amdgcn_exp2f(fmaf(sa1[2 * r], EXPC, mneg));
      float e3 = __builtin_amdgcn_exp2f(fmaf(sa1[2 * r + 1], EXPC, mneg));
      rs0 += e0; rs1 += e1; rs2 += e2; rs3 += e3;
      pw0[r] = pk2(e0, e1);
      pw1[r] = pk2(e2, e3);
    }
    lsum += (rs0 + rs1) + (rs2 + rs3);

    // ---- build PV A-frags: permlane32_swap redistributes packed halves ----
    // frag kk = kb2*2+ks covers keys kb2*32 + ks*16 + hi*8 + j
    unsigned f[4][4];
#pragma unroll
    for (int ks = 0; ks < 2; ++ks) {
      unsigned a0 = pw0[ks * 4 + 0], a1 = pw0[ks * 4 + 1];
      unsigned b0 = pw0[ks * 4 + 2], b1 = pw0[ks * 4 + 3];
      asm("v_permlane32_swap_b32 %0, %1" : "+v"(a0), "+v"(b0));
      asm("v_permlane32_swap_b32 %0, %1" : "+v"(a1), "+v"(b1));
      f[ks][0] = a0; f[ks][1] = a1; f[ks][2] = b0; f[ks][3] = b1;
      unsigned c0 = pw1[ks * 4 + 0], c1 = pw1[ks * 4 + 1];
      unsigned d0 = pw1[ks * 4 + 2], d1 = pw1[ks * 4 + 3];
      asm("v_permlane32_swap_b32 %0, %1" : "+v"(c0), "+v"(d0));
      asm("v_permlane32_swap_b32 %0, %1" : "+v"(c1), "+v"(d1));
      f[2 + ks][0] = c0; f[2 + ks][1] = c1; f[2 + ks][2] = d0; f[2 + ks][3] = d1;
    }

    // ---- O += P V: B-frag = V[key][d] from Vs[d][key] rows (b128, swizzled) ----
    __builtin_amdgcn_s_setprio(1);
#pragma unroll
    for (int kk = 0; kk < 4; ++kk) {
      u32x4 fw = {f[kk][0], f[kk][1], f[kk][2], f[kk][3]};
      bf16x8 pa = __builtin_bit_cast(bf16x8, fw);
      bf16x8 v0 = *(const bf16x8*)(&Vs[cur][r31 * 64 + (((kk * 2 + hi) ^ lsw) << 3)]);
      bf16x8 v1 = *(const bf16x8*)(&Vs[cur][(32 + r31) * 64 + (((kk * 2 + hi) ^ lsw) << 3)]);
      o0 = __builtin_amdgcn_mfma_f32_32x32x16_bf16(pa, v0, o0, 0, 0, 0);
      o1 = __builtin_amdgcn_mfma_f32_32x32x16_bf16(pa, v1, o1, 0, 0, 0);
    }
    __builtin_amdgcn_s_setprio(0);

    __syncthreads();  // prefetch drained (hidden under compute) + buffer swap
  }

  // ---- epilogue: combine halves (__shfl_xor), normalize, store ----
  lsum += __shfl_xor(lsum, 32, 64);
  float inv = 1.0f / lsum;
  const int b = bh >> 4, h = bh & 15;
  __bf16* abase = ao + ((size_t)b * 2048 + nbase) * 1024 + h * 64 + r31;
#pragma unroll
  for (int r = 0; r < 16; ++r) {
    int qrow = (r & 3) + 8 * (r >> 2) + 4 * hi;
    float ir = __shfl(inv, qrow, 64);
    abase[(size_t)qrow * 1024] = (__bf16)(o0[r] * ir);
    abase[(size_t)qrow * 1024 + 32] = (__bf16)(o1[r] * ir);
  }
}

extern "C" void kernel_launch(void* const* d_in, const int* in_sizes, int n_in,
                              void* d_out, int out_size, void* d_ws, size_t ws_size,
                              hipStream_t stream) {
  (void)in_sizes; (void)n_in; (void)out_size; (void)ws_size;
  const float* x = (const float*)d_in[0];      // [4,2048,1024]
  const float* w_qkv = (const float*)d_in[1];  // [1024,3072]
  const float* w_out = (const float*)d_in[2];  // [1024,1024]
  float* out = (float*)d_out;                  // [4,2048,1024]

  char* p = (char*)d_ws;
  __bf16* xb    = (__bf16*)p; p += (size_t)8192 * 1024 * 2;  // x bf16 [8192][1024]
  __bf16* wqkvT = (__bf16*)p; p += (size_t)3072 * 1024 * 2;  // w_qkv^T [3072][1024]
  __bf16* woutT = (__bf16*)p; p += (size_t)1024 * 1024 * 2;  // w_out^T [1024][1024]
  __bf16* qb    = (__bf16*)p; p += (size_t)64 * 2048 * 64 * 2;  // [bh][n][d]
  __bf16* kb    = (__bf16*)p; p += (size_t)64 * 2048 * 64 * 2;  // [bh][n][d]
  __bf16* vb    = (__bf16*)p; p += (size_t)64 * 64 * 2048 * 2;  // [bh][d][n]
  __bf16* ao    = (__bf16*)p; p += (size_t)8192 * 1024 * 2;     // [b*n][h*d]

  k_cvt<<<8192, 256, 0, stream>>>(x, xb, 2097152);
  k_tcvt<<<dim3(96, 32), dim3(32, 8), 0, stream>>>(w_qkv, wqkvT, 3072, 1024);
  k_tcvt<<<dim3(32, 32), dim3(32, 8), 0, stream>>>(w_out, woutT, 1024, 1024);
  k_gemm_qkv<<<dim3(64, 24), 256, 0, stream>>>(xb, wqkvT, qb, kb, vb);
  k_attn<<<dim3(1024), dim3(256), 0, stream>>>(qb, kb, vb, ao);
  k_gemm_out<<<dim3(64, 8), 256, 0, stream>>>(ao, woutT, out);
}